// Round 1
// baseline (445.358 us; speedup 1.0000x reference)
//
#include <hip/hip_runtime.h>

// MultipleMappings: out[b,s,e] = sum_d X[b,s,d] * W[lang[b],e,d], passthrough if lang<0
// B=64, S=4096, D=256, L=16. fp32 I/O, bf16 MFMA compute (threshold = 2% of ref absmax).

typedef __attribute__((ext_vector_type(8))) short bf16x8;
typedef __attribute__((ext_vector_type(16))) float f32x16;

#define S_DIM 4096
#define D_DIM 256
#define BM 128          // rows per block
#define BN 256          // full N per block -> X read once from HBM
#define BK 64           // k-chunk
#define LDK 72          // BK + 8 pad: stride 144 B = 36 banks == 4 mod 32 (balanced b128 reads)
#define NT 256          // 4 waves

static __device__ __forceinline__ unsigned short f2bf(float f) {
    // round-to-nearest-even fp32 -> bf16 (no NaN handling; inputs are finite randoms)
    unsigned int u = __float_as_uint(f);
    return (unsigned short)((u + 0x7fffu + ((u >> 16) & 1u)) >> 16);
}

// Pre-kernel: mapping fp32 (16x256x256) -> bf16 in workspace (2 MiB, L2-resident)
__global__ void cvt_w_kernel(const float* __restrict__ w, unsigned short* __restrict__ wb) {
    int i = (blockIdx.x * 256 + threadIdx.x) * 4;
    float4 v = *(const float4*)(w + i);
    ushort4 p;
    p.x = f2bf(v.x); p.y = f2bf(v.y); p.z = f2bf(v.z); p.w = f2bf(v.w);
    *(ushort4*)(wb + i) = p;
}

__global__ __launch_bounds__(NT, 2) void MultipleMappings_5952824672291_kernel(
    const float* __restrict__ X, const unsigned short* __restrict__ Wb,
    const int* __restrict__ pair_id, float* __restrict__ Y)
{
    __shared__ unsigned short ldsA[BM * LDK];   // 18 KiB
    __shared__ unsigned short ldsW[BN * LDK];   // 36 KiB   (54 KiB total -> 2 blocks/CU)

    const int b = blockIdx.y;
    const int t = threadIdx.x;
    const long base = ((long)b * S_DIM + (long)blockIdx.x * BM) * D_DIM;
    const float* Xb = X + base;
    float* Yb = Y + base;
    const int lang = pair_id[b];

    if (lang < 0) {
        // passthrough: copy 128x256 fp32 tile (contiguous)
        #pragma unroll
        for (int i = 0; i < 32; ++i) {
            int f4 = t + i * NT;
            *(float4*)(Yb + (long)f4 * 4) = *(const float4*)(Xb + (long)f4 * 4);
        }
        return;
    }

    const unsigned short* Wl = Wb + (size_t)lang * (D_DIM * D_DIM);

    const int lane  = t & 63;
    const int wave  = t >> 6;      // 0..3
    const int wr    = wave >> 1;   // 0..1  (row group: 64 rows)
    const int wc    = wave & 1;    // 0..1  (col group: 128 cols)
    const int lrow  = lane & 31;
    const int khalf = lane >> 5;   // A/B operand: k = kstep*16 + khalf*8 + j

    f32x16 acc[2][4] = {};

    for (int kc = 0; kc < 4; ++kc) {
        __syncthreads();
        // stage A chunk: 128 rows x 64 k, fp32 -> bf16. 8 float4 per thread, coalesced.
        #pragma unroll
        for (int i = 0; i < 8; ++i) {
            int flat = t + i * NT;
            int row = flat >> 4, c4 = flat & 15;
            float4 v = *(const float4*)(Xb + row * D_DIM + kc * BK + c4 * 4);
            ushort4 p;
            p.x = f2bf(v.x); p.y = f2bf(v.y); p.z = f2bf(v.z); p.w = f2bf(v.w);
            *(ushort4*)&ldsA[row * LDK + c4 * 4] = p;
        }
        // stage W chunk: 256 rows x 64 k bf16. 8 x 16B per thread, coalesced from L2.
        #pragma unroll
        for (int i = 0; i < 8; ++i) {
            int flat = t + i * NT;
            int row = flat >> 3, c8 = flat & 7;
            bf16x8 v = *(const bf16x8*)(Wl + row * D_DIM + kc * BK + c8 * 8);
            *(bf16x8*)&ldsW[row * LDK + c8 * 8] = v;
        }
        __syncthreads();
        // compute: 4 ksteps of 16; per kstep: 2 A-frags + 4 B-frags -> 8 MFMAs
        #pragma unroll
        for (int kk = 0; kk < 4; ++kk) {
            int k = kk * 16 + khalf * 8;
            bf16x8 af[2], bfr[4];
            #pragma unroll
            for (int rt = 0; rt < 2; ++rt)
                af[rt] = *(const bf16x8*)&ldsA[(wr * 64 + rt * 32 + lrow) * LDK + k];
            #pragma unroll
            for (int ct = 0; ct < 4; ++ct)
                bfr[ct] = *(const bf16x8*)&ldsW[(wc * 128 + ct * 32 + lrow) * LDK + k];
            #pragma unroll
            for (int rt = 0; rt < 2; ++rt)
                #pragma unroll
                for (int ct = 0; ct < 4; ++ct)
                    acc[rt][ct] = __builtin_amdgcn_mfma_f32_32x32x16_bf16(
                        af[rt], bfr[ct], acc[rt][ct], 0, 0, 0);
        }
    }

    // epilogue: C/D layout col=lane&31, row=(reg&3)+8*(reg>>2)+4*khalf  [m74/m101]
    #pragma unroll
    for (int rt = 0; rt < 2; ++rt) {
        #pragma unroll
        for (int ct = 0; ct < 4; ++ct) {
            const int colg = wc * 128 + ct * 32 + lrow;
            #pragma unroll
            for (int r = 0; r < 16; ++r) {
                int rowg = wr * 64 + rt * 32 + 4 * khalf + (r & 3) + 8 * (r >> 2);
                Yb[(long)rowg * D_DIM + colg] = acc[rt][ct][r];
            }
        }
    }
}

extern "C" void kernel_launch(void* const* d_in, const int* in_sizes, int n_in,
                              void* d_out, int out_size, void* d_ws, size_t ws_size,
                              hipStream_t stream) {
    const float* X   = (const float*)d_in[0];   // right_emb (64,4096,256) fp32
    const float* W   = (const float*)d_in[1];   // mapping (16,256,256) fp32
    const int*   pid = (const int*)d_in[2];     // pair_id (64,1) int32
    float*       Y   = (float*)d_out;
    unsigned short* Wbf = (unsigned short*)d_ws; // 2 MiB bf16 mapping

    // 16*256*256 = 1,048,576 elems; 4 per thread, 256 threads -> 1024 blocks
    cvt_w_kernel<<<dim3(1024), dim3(256), 0, stream>>>(W, Wbf);

    dim3 grid(S_DIM / BM, 64);  // (32, 64) = 2048 blocks
    MultipleMappings_5952824672291_kernel<<<grid, dim3(NT), 0, stream>>>(X, Wbf, pid, Y);
}

// Round 2
// 442.871 us; speedup vs baseline: 1.0056x; 1.0056x over previous
//
#include <hip/hip_runtime.h>

// MultipleMappings: out[b,s,e] = sum_d X[b,s,d] * W[lang[b],e,d], passthrough if lang<0
// B=64, S=4096, D=256, L=16. fp32 I/O, bf16 MFMA compute.
// Round 2: 64x256 block tile, 3 blocks/CU, global_load_lds DMA staging with
// XOR-swizzled LDS (DMA forbids padding: dest = wave-uniform base + lane*16).

typedef __attribute__((ext_vector_type(8))) short bf16x8;
typedef __attribute__((ext_vector_type(16))) float f32x16;

#define S_DIM 4096
#define D_DIM 256
#define BM 64
#define BK 64
#define NT 256

static __device__ __forceinline__ unsigned short f2bf(float f) {
    unsigned int u = __float_as_uint(f);
    return (unsigned short)((u + 0x7fffu + ((u >> 16) & 1u)) >> 16);
}

// pack two fp32 -> two bf16 (lo in low half), round-to-nearest-even
static __device__ __forceinline__ unsigned int pack_bf2(float lo, float hi) {
    unsigned int a = __float_as_uint(lo), b = __float_as_uint(hi);
    a += 0x7fffu + ((a >> 16) & 1u);
    b += 0x7fffu + ((b >> 16) & 1u);
    return (a >> 16) | (b & 0xffff0000u);
}

// 16-byte global -> LDS DMA. Dest is wave-uniform base + lane*16; we pass each
// lane's own slot ptr (first lane's value is the base, layout is slot-ordered).
static __device__ __forceinline__ void dma16(const void* g, void* l) {
    __builtin_amdgcn_global_load_lds(
        (const __attribute__((address_space(1))) unsigned int*)g,
        (__attribute__((address_space(3))) unsigned int*)l, 16, 0, 0);
}

// Pre-kernel: mapping fp32 (16x256x256) -> bf16 in workspace (2 MiB, L2-resident)
__global__ void cvt_w_kernel(const float* __restrict__ w, unsigned short* __restrict__ wb) {
    int i = (blockIdx.x * 256 + threadIdx.x) * 4;
    float4 v = *(const float4*)(w + i);
    ushort4 p;
    p.x = f2bf(v.x); p.y = f2bf(v.y); p.z = f2bf(v.z); p.w = f2bf(v.w);
    *(ushort4*)(wb + i) = p;
}

__global__ __launch_bounds__(NT, 3) void MultipleMappings_5952824672291_kernel(
    const float* __restrict__ X, const unsigned short* __restrict__ Wb,
    const int* __restrict__ pair_id, float* __restrict__ Y)
{
    // Swizzled layouts (byte offsets):
    //  ldsW: (row, kg) -> row*128 + ((kg ^ (row&7)) * 16),  kg in [0,8)  (8 bf16/group)  32 KiB
    //  ldsA: (row, kg) -> row*256 + ((kg ^ (row&15)) * 16), kg in [0,16) (4 fp32/group)  16 KiB
    __shared__ unsigned short ldsW[256 * 64];
    __shared__ float ldsA[64 * 64];

    const int b = blockIdx.y;
    const int t = threadIdx.x;
    const long base = ((long)b * S_DIM + (long)blockIdx.x * BM) * D_DIM;
    const float* Xb = X + base;
    float* Yb = Y + base;
    const int lang = pair_id[b];

    if (lang < 0) {
        // passthrough: copy 64x256 fp32 tile
        #pragma unroll
        for (int i = 0; i < 16; ++i) {
            int f4 = t + i * NT;
            *(float4*)(Yb + (long)f4 * 4) = *(const float4*)(Xb + (long)f4 * 4);
        }
        return;
    }

    const unsigned short* Wl = Wb + (size_t)lang * (D_DIM * D_DIM);

    const int lane  = t & 63;
    const int wave  = t >> 6;      // 4 waves
    const int wr    = wave >> 1;   // 0..1: 32-row group
    const int wc    = wave & 1;    // 0..1: 128-col group
    const int lrow  = lane & 31;
    const int khalf = lane >> 5;   // operand k = kk*16 + khalf*8 + j

    f32x16 acc[4] = {};

    for (int kc = 0; kc < 4; ++kc) {
        __syncthreads();   // protect LDS reuse from previous kc
        // W chunk: 256 rows x 64 k bf16 = 2048 16B slots; 8 DMA issues/thread
        #pragma unroll
        for (int j = 0; j < 8; ++j) {
            int slot = j * NT + t;
            int row = slot >> 3, kgl = slot & 7;
            int kgs = kgl ^ (row & 7);              // source group living at this slot
            dma16(Wl + row * D_DIM + kc * BK + kgs * 8, (char*)ldsW + slot * 16);
        }
        // A chunk: 64 rows x 64 k fp32 = 1024 16B slots; 4 DMA issues/thread
        #pragma unroll
        for (int j = 0; j < 4; ++j) {
            int slot = j * NT + t;
            int row = slot >> 4, kgl = slot & 15;
            int kgs = kgl ^ (row & 15);
            dma16(Xb + row * D_DIM + kc * BK + kgs * 4, (char*)ldsA + slot * 16);
        }
        __syncthreads();   // compiler drains vmcnt(0) before s_barrier -> DMA complete
        #pragma unroll
        for (int kk = 0; kk < 4; ++kk) {
            const int k = kk * 16 + khalf * 8;
            // A fragment: 8 consecutive fp32 -> 2 swizzled float4 reads + cvt to bf16
            const int arow = wr * 32 + lrow;
            const int am = arow & 15;
            const int kg0 = k >> 2;
            float4 a0 = *(const float4*)((char*)ldsA + arow * 256 + ((kg0 ^ am) * 16));
            float4 a1 = *(const float4*)((char*)ldsA + arow * 256 + (((kg0 + 1) ^ am) * 16));
            union { bf16x8 v; unsigned int u[4]; } af;
            af.u[0] = pack_bf2(a0.x, a0.y);
            af.u[1] = pack_bf2(a0.z, a0.w);
            af.u[2] = pack_bf2(a1.x, a1.y);
            af.u[3] = pack_bf2(a1.z, a1.w);
            const int kg = k >> 3;
            #pragma unroll
            for (int ct = 0; ct < 4; ++ct) {
                const int brow = wc * 128 + ct * 32 + lrow;
                bf16x8 bfv = *(const bf16x8*)((char*)ldsW + brow * 128 + ((kg ^ (brow & 7)) * 16));
                acc[ct] = __builtin_amdgcn_mfma_f32_32x32x16_bf16(af.v, bfv, acc[ct], 0, 0, 0);
            }
        }
    }

    // C/D layout: col=lane&31, row=(reg&3)+8*(reg>>2)+4*khalf  [m74/m101]
    #pragma unroll
    for (int ct = 0; ct < 4; ++ct) {
        const int colg = wc * 128 + ct * 32 + lrow;
        #pragma unroll
        for (int r = 0; r < 16; ++r) {
            int rowg = wr * 32 + 4 * khalf + (r & 3) + 8 * (r >> 2);
            Yb[(long)rowg * D_DIM + colg] = acc[ct][r];
        }
    }
}

extern "C" void kernel_launch(void* const* d_in, const int* in_sizes, int n_in,
                              void* d_out, int out_size, void* d_ws, size_t ws_size,
                              hipStream_t stream) {
    const float* X   = (const float*)d_in[0];   // right_emb (64,4096,256) fp32
    const float* W   = (const float*)d_in[1];   // mapping (16,256,256) fp32
    const int*   pid = (const int*)d_in[2];     // pair_id (64,1) int32
    float*       Y   = (float*)d_out;
    unsigned short* Wbf = (unsigned short*)d_ws;

    cvt_w_kernel<<<dim3(1024), dim3(256), 0, stream>>>(W, Wbf);

    dim3 grid(S_DIM / BM, 64);   // (64, 64) = 4096 blocks, 16/CU
    MultipleMappings_5952824672291_kernel<<<grid, dim3(NT), 0, stream>>>(X, Wbf, pid, Y);
}